// Round 1
// baseline (4681.598 us; speedup 1.0000x reference)
//
#include <hip/hip_runtime.h>

// SimpleMACELayer on gfx950 — round 1 (fp32/f16 vector baseline, fdot2 inner loop)
//
// Math: out[a,o2] = b[o2] + sum_{e: dst(e)=a} sum_{kk,h} u[e,h,kk] * F[kk,o2,h]
//   F_p[h,o2,k]  = sum_o tpw[p,h,o] * W_lin[o2, o*16 + l3^2 + k]   (precomputed in d_ws, f16)
//   u[e,h,kk]    = sum_i src[e,h,l1^2+i] * A_e[i,kk]
//   A_e[i,kk]    = sum_j Y_e[l2^2+j] * cg[l1^2+i, l2^2+j, l3^2+k]
// kk enumerates (path, k-within-l3) pairs; total 99. W_lin folded into tp_weights
// => 64 atomics/edge (not 1024), no agg workspace, 2x fewer FLOPs than reference.

#define NIR 16
#define HID 64
#define NOUT 64
#define NPATH 23
#define NKK 99
#define EPB 16      // edges per block
#define NWAVE 4
#define THREADS 256

typedef _Float16 f16;
typedef _Float16 f16x2 __attribute__((ext_vector_type(2)));

__device__ __constant__ int P_L1[NPATH] = {0,0,0,0, 1,1,1,1,1,1, 2,2,2,2,2,2,2, 3,3,3,3,3,3};
__device__ __constant__ int P_L2[NPATH] = {0,1,2,3, 0,1,1,2,2,3, 0,1,1,2,2,3,3, 0,1,2,2,3,3};
__device__ __constant__ int P_L3[NPATH] = {0,1,2,3, 1,0,2,1,3,2, 2,1,3,0,2,1,3, 3,2,1,3,0,2};

__device__ __constant__ int PK_P[NKK] = {
  0,
  1,1,1,
  2,2,2,2,2,
  3,3,3,3,3,3,3,
  4,4,4,
  5,
  6,6,6,6,6,
  7,7,7,
  8,8,8,8,8,8,8,
  9,9,9,9,9,
  10,10,10,10,10,
  11,11,11,
  12,12,12,12,12,12,12,
  13,
  14,14,14,14,14,
  15,15,15,
  16,16,16,16,16,16,16,
  17,17,17,17,17,17,17,
  18,18,18,18,18,
  19,19,19,
  20,20,20,20,20,20,20,
  21,
  22,22,22,22,22};

__device__ __constant__ int PK_K[NKK] = {
  0,
  0,1,2,
  0,1,2,3,4,
  0,1,2,3,4,5,6,
  0,1,2,
  0,
  0,1,2,3,4,
  0,1,2,
  0,1,2,3,4,5,6,
  0,1,2,3,4,
  0,1,2,3,4,
  0,1,2,
  0,1,2,3,4,5,6,
  0,
  0,1,2,3,4,
  0,1,2,
  0,1,2,3,4,5,6,
  0,1,2,3,4,5,6,
  0,1,2,3,4,
  0,1,2,
  0,1,2,3,4,5,6,
  0,
  0,1,2,3,4};

__device__ __forceinline__ f16x2 u2h(unsigned v) {
  union { unsigned u; f16x2 h; } c; c.u = v; return c.h;
}

// ---------------- F precompute: F[kk][o2][h] (f16) = sum_o tpw[p][h][o]*wlin[o2][o*16+c3]
__global__ __launch_bounds__(256) void compute_F(const float* __restrict__ tpw,
                                                 const float* __restrict__ wlin,
                                                 f16* __restrict__ F) {
  int kk = blockIdx.x;
  int p  = PK_P[kk];
  int k3 = PK_K[kk];
  int l3 = P_L3[p];
  int c3 = l3 * l3 + k3;

  __shared__ float wl[64][65];   // wl[o2][o] = wlin[o2][o*16+c3]
  int tid = threadIdx.x;
  for (int idx = tid; idx < 64 * 64; idx += 256) {
    int o2 = idx >> 6, o = idx & 63;
    wl[o2][o] = wlin[o2 * 1024 + o * 16 + c3];
  }
  __syncthreads();

  int h = tid & 63, og = tid >> 6;   // og: 4 groups of 16 o2
  float acc[16];
#pragma unroll
  for (int m = 0; m < 16; ++m) acc[m] = 0.f;
  const float* tw = tpw + (p * 64 + h) * 64;
  for (int o = 0; o < 64; ++o) {
    float w = tw[o];
#pragma unroll
    for (int m = 0; m < 16; ++m) acc[m] += w * wl[og * 16 + m][o];
  }
  f16* dst = F + (size_t)(kk * 64 + og * 16) * 64 + h;
#pragma unroll
  for (int m = 0; m < 16; ++m) dst[m * 64] = (f16)acc[m];
}

// ---------------- out init: out[a][o2] = b[o2]
__global__ void init_out(float* __restrict__ out, const float* __restrict__ b, int n) {
  int i = blockIdx.x * 256 + threadIdx.x;
  if (i < n) out[i] = b[i & 63];
}

// ---------------- main edge kernel
// LDS strides chosen so uniform-stride b128 access patterns land on stride ≡ 4 (mod 32)
// dwords → worst-case 4-way bank conflict (1.58x on minor phases only).
__global__ __launch_bounds__(THREADS, 3) void edge_kernel(
    const float* __restrict__ nf, const float* __restrict__ ev,
    const int* __restrict__ eidx, const float* __restrict__ cg,
    const f16* __restrict__ F, float* __restrict__ out, int NE) {

  __shared__ f16 sSrc[EPB * 1160];          // [e][i][h]: e-stride 1160 f16 (2320B), i-stride 72 f16
  __shared__ float sY[EPB][NIR];
  __shared__ f16 sA[NWAVE][EPB][8];
  __shared__ f16 sU[NWAVE * 16 * 72];       // [wave][e][h]: wave-stride 1152, e-stride 72
  __shared__ int sDst[EPB];
  __shared__ int sSrcA[EPB];

  int tid = threadIdx.x;

  // --- phase 0: edge meta + spherical harmonics
  if (tid < EPB) {
    int eg = blockIdx.x * EPB + tid;
    int sa = 0, da = -1;
    float x = 0.f, y = 0.f, z = 0.f;
    if (eg < NE) {
      sa = eidx[eg];
      da = eidx[NE + eg];
      x = ev[3 * eg + 0]; y = ev[3 * eg + 1]; z = ev[3 * eg + 2];
    }
    sSrcA[tid] = sa;
    sDst[tid] = da;
    float x2 = x * x, y2 = y * y, z2 = z * z;
    sY[tid][0]  = 0.28209479177387814f;
    sY[tid][1]  = 0.4886025119029199f * y;
    sY[tid][2]  = 0.4886025119029199f * z;
    sY[tid][3]  = 0.4886025119029199f * x;
    sY[tid][4]  = 1.0925484305920792f * x * y;
    sY[tid][5]  = 1.0925484305920792f * y * z;
    sY[tid][6]  = 0.31539156525252005f * (3.0f * z2 - 1.0f);
    sY[tid][7]  = 1.0925484305920792f * x * z;
    sY[tid][8]  = 0.5462742152960396f * (x2 - y2);
    sY[tid][9]  = 0.5900435899266435f * y * (3.0f * x2 - y2);
    sY[tid][10] = 2.890611442640554f * x * y * z;
    sY[tid][11] = 0.4570457994644658f * y * (5.0f * z2 - 1.0f);
    sY[tid][12] = 0.3731763325901154f * z * (5.0f * z2 - 3.0f);
    sY[tid][13] = 0.4570457994644658f * x * (5.0f * z2 - 1.0f);
    sY[tid][14] = 1.445305721320277f  * z * (x2 - y2);
    sY[tid][15] = 0.5900435899266435f * x * (x2 - 3.0f * y2);
  }
  __syncthreads();

  // --- phase 1: gather+transpose src features -> sSrc[e][i][h] (f16)
  {
    int e = tid >> 4, tt = tid & 15;
    int atom = sSrcA[e];
    const float4* src4 = (const float4*)nf + (size_t)atom * 256;
#pragma unroll
    for (int r = 0; r < 16; ++r) {
      int fi = tt + (r << 4);
      float4 v = src4[fi];
      int hh = fi >> 2, i0 = (fi & 3) << 2;
      f16* dst = &sSrc[e * 1160 + i0 * 72 + hh];
      dst[0]   = (f16)v.x;
      dst[72]  = (f16)v.y;
      dst[144] = (f16)v.z;
      dst[216] = (f16)v.w;
    }
  }
  __syncthreads();

  // --- main loop: waves round-robin kk = wave + 4*it
  int wave = tid >> 6, lane = tid & 63;
  int lx = lane & 7, ly = lane >> 3;     // o2 = lx*8+oj ; e = ly*2+ei
  float acc[2][8];
#pragma unroll
  for (int ei = 0; ei < 2; ++ei)
#pragma unroll
    for (int oj = 0; oj < 8; ++oj) acc[ei][oj] = 0.f;

  for (int it = 0; it < 25; ++it) {
    int kk = wave + (it << 2);
    bool act = (kk < NKK);
    int p = 0, k3 = 0, l1 = 0, l2 = 0, l3 = 0;
    if (act) { p = PK_P[kk]; k3 = PK_K[kk]; l1 = P_L1[p]; l2 = P_L2[p]; l3 = P_L3[p]; }
    int ni = 2 * l1 + 1, nj = 2 * l2 + 1;
    int b1 = l1 * l1, b2 = l2 * l2, kg = l3 * l3 + k3;

    // A phase: A[e][i] = sum_j Y[e][b2+j]*cg[b1+i][b2+j][kg]
    if (act) {
      int e = lane >> 2;
      for (int i = lane & 3; i < ni; i += 4) {
        float a = 0.f;
        const float* cgp = cg + ((b1 + i) * 16 + b2) * 16 + kg;
        for (int j = 0; j < nj; ++j) a += sY[e][b2 + j] * cgp[j * 16];
        sA[wave][e][i] = (f16)a;
      }
    }
    __syncthreads();

    // U phase: u[e][h] = sum_i src[e][h][b1+i]*A[e][i]  (f16 packed math)
    if (act) {
      int e = lane >> 2, h0 = (lane & 3) << 4;
      f16x2 uacc[8] = {};
      for (int i = 0; i < ni; ++i) {
        f16 a = sA[wave][e][i];
        f16x2 av = {a, a};
        const f16x2* sp = (const f16x2*)&sSrc[e * 1160 + (b1 + i) * 72 + h0];
#pragma unroll
        for (int q = 0; q < 8; ++q) uacc[q] += av * sp[q];
      }
      f16x2* up = (f16x2*)&sU[wave * 1152 + e * 72 + h0];
#pragma unroll
      for (int q = 0; q < 8; ++q) up[q] = uacc[q];
    }
    __syncthreads();

    // FMA phase: acc[ei][oj] += sum_h u[e][h]*F[kk][o2][h]  (fdot2, fp32 accum)
    if (act) {
      const uint4* Fb = (const uint4*)F + (size_t)(kk * 64 + lx * 8) * 8;
#pragma unroll
      for (int h8 = 0; h8 < 8; ++h8) {
        uint4 u0 = *(const uint4*)&sU[wave * 1152 + (ly * 2 + 0) * 72 + h8 * 8];
        uint4 u1 = *(const uint4*)&sU[wave * 1152 + (ly * 2 + 1) * 72 + h8 * 8];
        f16x2 ua0[4] = {u2h(u0.x), u2h(u0.y), u2h(u0.z), u2h(u0.w)};
        f16x2 ua1[4] = {u2h(u1.x), u2h(u1.y), u2h(u1.z), u2h(u1.w)};
#pragma unroll
        for (int oj = 0; oj < 8; ++oj) {
          uint4 fv = Fb[oj * 8 + h8];
          f16x2 f0 = u2h(fv.x), f1 = u2h(fv.y), f2 = u2h(fv.z), f3 = u2h(fv.w);
          acc[0][oj] = __builtin_amdgcn_fdot2(ua0[0], f0, acc[0][oj], false);
          acc[0][oj] = __builtin_amdgcn_fdot2(ua0[1], f1, acc[0][oj], false);
          acc[0][oj] = __builtin_amdgcn_fdot2(ua0[2], f2, acc[0][oj], false);
          acc[0][oj] = __builtin_amdgcn_fdot2(ua0[3], f3, acc[0][oj], false);
          acc[1][oj] = __builtin_amdgcn_fdot2(ua1[0], f0, acc[1][oj], false);
          acc[1][oj] = __builtin_amdgcn_fdot2(ua1[1], f1, acc[1][oj], false);
          acc[1][oj] = __builtin_amdgcn_fdot2(ua1[2], f2, acc[1][oj], false);
          acc[1][oj] = __builtin_amdgcn_fdot2(ua1[3], f3, acc[1][oj], false);
        }
      }
    }
    __syncthreads();
  }

  // --- cross-wave reduction (overlay on sSrc) + atomic scatter to out
  float* red = (float*)sSrc;   // 4 waves * 16e * 64o2 fp32 = 16 KB (fits in sSrc region)
#pragma unroll
  for (int ei = 0; ei < 2; ++ei)
#pragma unroll
    for (int oj = 0; oj < 8; ++oj)
      red[(wave * 16 + ly * 2 + ei) * 64 + lx * 8 + oj] = acc[ei][oj];
  __syncthreads();

#pragma unroll
  for (int rep = 0; rep < 4; ++rep) {
    int oi = tid + rep * 256;
    int e = oi >> 6, o2 = oi & 63;
    float s = red[(0 * 16 + e) * 64 + o2] + red[(1 * 16 + e) * 64 + o2] +
              red[(2 * 16 + e) * 64 + o2] + red[(3 * 16 + e) * 64 + o2];
    int da = sDst[e];
    if (da >= 0) unsafeAtomicAdd(out + (size_t)da * 64 + o2, s);
  }
}

extern "C" void kernel_launch(void* const* d_in, const int* in_sizes, int n_in,
                              void* d_out, int out_size, void* d_ws, size_t ws_size,
                              hipStream_t stream) {
  const float* nf   = (const float*)d_in[0];  // [NA,64,16]
  const float* ev   = (const float*)d_in[1];  // [NE,3]
  const int*   eidx = (const int*)d_in[2];    // [2,NE]
  const float* cg   = (const float*)d_in[3];  // [16,16,16]
  const float* tpw  = (const float*)d_in[4];  // [23,64,64]
  const float* wlin = (const float*)d_in[5];  // [64,1024]
  const float* blin = (const float*)d_in[6];  // [64]
  float* out = (float*)d_out;                 // [NA,64]

  int NA = in_sizes[0] / (HID * NIR);
  int NE = in_sizes[1] / 3;
  f16* F = (f16*)d_ws;                        // 99*64*64 f16 = 811 KB

  compute_F<<<NKK, 256, 0, stream>>>(tpw, wlin, F);
  init_out<<<(NA * NOUT + 255) / 256, 256, 0, stream>>>(out, blin, NA * NOUT);
  edge_kernel<<<(NE + EPB - 1) / EPB, THREADS, 0, stream>>>(nf, ev, eidx, cg, F, out, NE);
}

// Round 2
// 1017.382 us; speedup vs baseline: 4.6016x; 4.6016x over previous
//
#include <hip/hip_runtime.h>

// SimpleMACELayer on gfx950 — round 2: two-stage MFMA pipeline.
//
//   F[h][o2][kk]  = sum_o tpw[p(kk)][h][o] * W_lin[o2][o*16 + kg(kk)]   (f16, kk padded to 128 w/ zeros, in d_ws)
//   A_e[kk][i]    = sum_j Y_e[b2+j] * cg[i][b2+j][kg(kk)]  (dense over i=0..15, zero outside [b1,b1+ni))
//   U[e][h][kk]   = sum_i A_e[kk][i] * src[e][h][i]                      (GEMM-1: mfma 16x16x16 f16, per edge)
//   out[dst(e),:] += sum_{h,kk} U[e][h][kk] * F[h][:][kk]                (GEMM-2: mfma 16x16x32 f16, K=8192)
//
// Round-1 post-mortem: VALUBusy 14.8% == pure fdot2 issue time; 85% stall on per-lane
// global F loads (68 VGPRs, no overlap across 50 barriers). Fix: MFMA + register-resident
// src fragments (coalesced float4 == MFMA B-layout) + contiguous 16B F loads w/ lookahead.

#define NPATH 23
#define NKK 99
#define NKPAD 128
#define EPB 32
#define THREADS 256

typedef _Float16 f16;
typedef f16 f16x4 __attribute__((ext_vector_type(4)));
typedef f16 f16x8 __attribute__((ext_vector_type(8)));
typedef float f32x4 __attribute__((ext_vector_type(4)));

// per-kk tables (kk-major expansion of the 23 paths; k3 = kg - l3*l3)
__device__ __constant__ short PK_P[NKK] = {
  0, 1,1,1, 2,2,2,2,2, 3,3,3,3,3,3,3, 4,4,4, 5, 6,6,6,6,6, 7,7,7,
  8,8,8,8,8,8,8, 9,9,9,9,9, 10,10,10,10,10, 11,11,11, 12,12,12,12,12,12,12,
  13, 14,14,14,14,14, 15,15,15, 16,16,16,16,16,16,16, 17,17,17,17,17,17,17,
  18,18,18,18,18, 19,19,19, 20,20,20,20,20,20,20, 21, 22,22,22,22,22};
__device__ __constant__ short KK_L1[NKK] = {
  0, 0,0,0, 0,0,0,0,0, 0,0,0,0,0,0,0, 1,1,1, 1, 1,1,1,1,1, 1,1,1,
  1,1,1,1,1,1,1, 1,1,1,1,1, 2,2,2,2,2, 2,2,2, 2,2,2,2,2,2,2,
  2, 2,2,2,2,2, 2,2,2, 2,2,2,2,2,2,2, 3,3,3,3,3,3,3,
  3,3,3,3,3, 3,3,3, 3,3,3,3,3,3,3, 3, 3,3,3,3,3};
__device__ __constant__ short KK_L2[NKK] = {
  0, 1,1,1, 2,2,2,2,2, 3,3,3,3,3,3,3, 0,0,0, 1, 1,1,1,1,1, 2,2,2,
  2,2,2,2,2,2,2, 3,3,3,3,3, 0,0,0,0,0, 1,1,1, 1,1,1,1,1,1,1,
  2, 2,2,2,2,2, 3,3,3, 3,3,3,3,3,3,3, 0,0,0,0,0,0,0,
  1,1,1,1,1, 2,2,2, 2,2,2,2,2,2,2, 3, 3,3,3,3,3};
__device__ __constant__ short KK_KG[NKK] = {
  0, 1,2,3, 4,5,6,7,8, 9,10,11,12,13,14,15, 1,2,3, 0, 4,5,6,7,8, 1,2,3,
  9,10,11,12,13,14,15, 4,5,6,7,8, 4,5,6,7,8, 1,2,3, 9,10,11,12,13,14,15,
  0, 4,5,6,7,8, 1,2,3, 9,10,11,12,13,14,15, 9,10,11,12,13,14,15,
  4,5,6,7,8, 1,2,3, 9,10,11,12,13,14,15, 0, 4,5,6,7,8};

// ---------------- zero F (incl. kk 99..127 pad)
__global__ void zero_ws(uint4* __restrict__ F) {
  F[blockIdx.x * 256 + threadIdx.x] = uint4{0, 0, 0, 0};
}

// ---------------- F[h][o2][kk] = sum_o tpw[p][h][o] * wlin[o2][o*16+kg]
__global__ __launch_bounds__(256) void compute_F(const float* __restrict__ tpw,
                                                 const float* __restrict__ wlin,
                                                 f16* __restrict__ F) {
  int kk = blockIdx.x;
  int p  = PK_P[kk];
  int c3 = KK_KG[kk];

  __shared__ float wl[64][65];
  int tid = threadIdx.x;
  for (int idx = tid; idx < 64 * 64; idx += 256) {
    int o2 = idx >> 6, o = idx & 63;
    wl[o2][o] = wlin[o2 * 1024 + o * 16 + c3];
  }
  __syncthreads();

  int h = tid & 63, og = tid >> 6;
  float acc[16];
#pragma unroll
  for (int m = 0; m < 16; ++m) acc[m] = 0.f;
  const float* tw = tpw + (p * 64 + h) * 64;
  for (int o = 0; o < 64; ++o) {
    float w = tw[o];
#pragma unroll
    for (int m = 0; m < 16; ++m) acc[m] += w * wl[og * 16 + m][o];
  }
#pragma unroll
  for (int m = 0; m < 16; ++m)
    F[(size_t)(h * 64 + og * 16 + m) * NKPAD + kk] = (f16)acc[m];
}

// ---------------- out init
__global__ void init_out(float* __restrict__ out, const float* __restrict__ b, int n) {
  int i = blockIdx.x * 256 + threadIdx.x;
  if (i < n) out[i] = b[i & 63];
}

// ---------------- main edge kernel
// LDS: sA[e][kk32][i16] f16 (32KB), sU[e][h16 x stride40 +8pad] f16 (40.5KB, reused as fp32 red)
__global__ __launch_bounds__(THREADS, 2) void edge_kernel(
    const float* __restrict__ nf, const float* __restrict__ ev,
    const int* __restrict__ eidx, const float* __restrict__ cg,
    const f16* __restrict__ F, float* __restrict__ out, int NE) {

  __shared__ float sY[EPB][16];
  __shared__ int sSrcA[EPB];
  __shared__ int sDst[EPB];
  __shared__ f16 sA[EPB * 32 * 16];   // [e][kkloc][i]
  __shared__ f16 sU[EPB * 648];       // [e][hloc] h-stride 40 f16, e-stride 648 f16

  int tid = threadIdx.x;
  int wave = tid >> 6, lane = tid & 63;
  int lm = lane & 15, lq = lane >> 4;

  // --- phase 0: edge meta + spherical harmonics
  if (tid < EPB) {
    int eg = blockIdx.x * EPB + tid;
    int sa = 0, da = -1;
    float x = 0.f, y = 0.f, z = 0.f;
    if (eg < NE) {
      sa = eidx[eg];
      da = eidx[NE + eg];
      x = ev[3 * eg + 0]; y = ev[3 * eg + 1]; z = ev[3 * eg + 2];
    }
    sSrcA[tid] = sa;
    sDst[tid] = da;
    float x2 = x * x, y2 = y * y, z2 = z * z;
    sY[tid][0]  = 0.28209479177387814f;
    sY[tid][1]  = 0.4886025119029199f * y;
    sY[tid][2]  = 0.4886025119029199f * z;
    sY[tid][3]  = 0.4886025119029199f * x;
    sY[tid][4]  = 1.0925484305920792f * x * y;
    sY[tid][5]  = 1.0925484305920792f * y * z;
    sY[tid][6]  = 0.31539156525252005f * (3.0f * z2 - 1.0f);
    sY[tid][7]  = 1.0925484305920792f * x * z;
    sY[tid][8]  = 0.5462742152960396f * (x2 - y2);
    sY[tid][9]  = 0.5900435899266435f * y * (3.0f * x2 - y2);
    sY[tid][10] = 2.890611442640554f * x * y * z;
    sY[tid][11] = 0.4570457994644658f * y * (5.0f * z2 - 1.0f);
    sY[tid][12] = 0.3731763325901154f * z * (5.0f * z2 - 3.0f);
    sY[tid][13] = 0.4570457994644658f * x * (5.0f * z2 - 1.0f);
    sY[tid][14] = 1.445305721320277f  * z * (x2 - y2);
    sY[tid][15] = 0.5900435899266435f * x * (x2 - 3.0f * y2);
  }
  __syncthreads();

  // --- register-resident src fragments (MFMA B-layout == nf layout, coalesced float4)
  // Sf[ei][ht]: B[k=i][n=h']: lane n=lm -> h'=lm, k-quad=lq -> i in [4lq,4lq+4)
  f16x4 Sf[8][4];
  int ebase = wave * 8;
#pragma unroll
  for (int ei = 0; ei < 8; ++ei) {
    const float4* src4 = (const float4*)nf + (size_t)sSrcA[ebase + ei] * 256;
#pragma unroll
    for (int ht = 0; ht < 4; ++ht) {
      float4 v = src4[(ht * 16 + lm) * 4 + lq];
      Sf[ei][ht] = f16x4{(f16)v.x, (f16)v.y, (f16)v.z, (f16)v.w};
    }
  }

  f32x4 acc[2][4];
#pragma unroll
  for (int mt = 0; mt < 2; ++mt)
#pragma unroll
    for (int ot = 0; ot < 4; ++ot) acc[mt][ot] = f32x4{0.f, 0.f, 0.f, 0.f};

  for (int kg = 0; kg < 4; ++kg) {
    // --- build A_e for kk in [kg*32, kg*32+32)  (sA safe: all waves past last G1 via loop barrier)
    {
      int kkl = tid & 31, ee0 = tid >> 5;
      int kkglob = kg * 32 + kkl;
#pragma unroll
      for (int rep = 0; rep < 4; ++rep) {
        int e = ee0 + 8 * rep;
        f16* dst = &sA[(e * 32 + kkl) * 16];
        *(f16x8*)dst = f16x8{0,0,0,0,0,0,0,0};
        *(f16x8*)(dst + 8) = f16x8{0,0,0,0,0,0,0,0};
        if (kkglob < NKK) {
          int l1 = KK_L1[kkglob], l2 = KK_L2[kkglob], kgi = KK_KG[kkglob];
          int b1 = l1 * l1, b2 = l2 * l2, ni = 2 * l1 + 1, nj = 2 * l2 + 1;
          for (int i = 0; i < ni; ++i) {
            float a = 0.f;
            const float* cgp = cg + ((b1 + i) * 16 + b2) * 16 + kgi;
            for (int j = 0; j < nj; ++j) a += sY[e][b2 + j] * cgp[j * 16];
            dst[b1 + i] = (f16)a;
          }
        }
      }
    }
    __syncthreads();

#pragma unroll
    for (int hg = 0; hg < 4; ++hg) {
      // --- GEMM-1: U[e][h'][kk] for my 8 edges (sU free: barrier at loop bottom)
#pragma unroll
      for (int ei = 0; ei < 8; ++ei) {
        int e = ebase + ei;
        f16x4 bS = Sf[ei][hg];
#pragma unroll
        for (int mt = 0; mt < 2; ++mt) {
          f16x4 aA = *(const f16x4*)&sA[(e * 32 + mt * 16 + lm) * 16 + lq * 4];
          f32x4 d = __builtin_amdgcn_mfma_f32_16x16x16f16(aA, bS, f32x4{0.f, 0.f, 0.f, 0.f}, 0, 0, 0);
          // D: col=lm -> h'=lm ; rows = mt*16 + lq*4 + r -> 4 consecutive kk
          f16x4 dh = {(f16)d[0], (f16)d[1], (f16)d[2], (f16)d[3]};
          *(f16x4*)&sU[e * 648 + lm * 40 + mt * 16 + lq * 4] = dh;
        }
      }
      __syncthreads();

      // --- GEMM-2: acc += U * F over this chunk; wave handles h' = wave + 4*hi
#pragma unroll
      for (int hi = 0; hi < 4; ++hi) {
        int hl = wave + 4 * hi;
        int h = hg * 16 + hl;
        f16x8 a0 = *(const f16x8*)&sU[(lm)      * 648 + hl * 40 + lq * 8];
        f16x8 a1 = *(const f16x8*)&sU[(16 + lm) * 648 + hl * 40 + lq * 8];
        const f16* Fb = F + (size_t)h * 64 * NKPAD + kg * 32 + lq * 8;
#pragma unroll
        for (int ot = 0; ot < 4; ++ot) {
          f16x8 b = *(const f16x8*)&Fb[(size_t)(ot * 16 + lm) * NKPAD];
          acc[0][ot] = __builtin_amdgcn_mfma_f32_16x16x32_f16(a0, b, acc[0][ot], 0, 0, 0);
          acc[1][ot] = __builtin_amdgcn_mfma_f32_16x16x32_f16(a1, b, acc[1][ot], 0, 0, 0);
        }
      }
      __syncthreads();
    }
  }

  // --- cross-wave reduction (overlay fp32 on sU) + atomic scatter
  float* red = (float*)sU;   // 4 waves * 32e * 64o2 * 4B = 32KB <= 41.4KB
#pragma unroll
  for (int mt = 0; mt < 2; ++mt)
#pragma unroll
    for (int ot = 0; ot < 4; ++ot) {
      f32x4 d = acc[mt][ot];
#pragma unroll
      for (int r = 0; r < 4; ++r) {
        int e = mt * 16 + lq * 4 + r;    // D row = e-local
        int o2 = ot * 16 + lm;           // D col = o2
        red[(wave * EPB + e) * 64 + o2] = d[r];
      }
    }
  __syncthreads();

#pragma unroll
  for (int rep = 0; rep < 8; ++rep) {
    int idx = tid + rep * 256;           // 0..2047
    int e = idx >> 6, o2 = idx & 63;
    float s = red[idx] + red[2048 + idx] + red[4096 + idx] + red[6144 + idx];
    int da = sDst[e];
    if (da >= 0) unsafeAtomicAdd(out + (size_t)da * 64 + o2, s);
  }
}

extern "C" void kernel_launch(void* const* d_in, const int* in_sizes, int n_in,
                              void* d_out, int out_size, void* d_ws, size_t ws_size,
                              hipStream_t stream) {
  const float* nf   = (const float*)d_in[0];  // [NA,64,16]
  const float* ev   = (const float*)d_in[1];  // [NE,3]
  const int*   eidx = (const int*)d_in[2];    // [2,NE]
  const float* cg   = (const float*)d_in[3];  // [16,16,16]
  const float* tpw  = (const float*)d_in[4];  // [23,64,64]
  const float* wlin = (const float*)d_in[5];  // [64,1024]
  const float* blin = (const float*)d_in[6];  // [64]
  float* out = (float*)d_out;                 // [NA,64]

  int NA = in_sizes[0] / 1024;
  int NE = in_sizes[1] / 3;
  f16* F = (f16*)d_ws;                        // 64*64*128 f16 = 1 MB

  zero_ws<<<(64 * 64 * NKPAD * 2 / 16 + 255) / 256, 256, 0, stream>>>((uint4*)F);
  compute_F<<<NKK, 256, 0, stream>>>(tpw, wlin, F);
  init_out<<<(NA * 64 + 255) / 256, 256, 0, stream>>>(out, blin, NA * 64);
  edge_kernel<<<(NE + EPB - 1) / EPB, THREADS, 0, stream>>>(nf, ev, eidx, cg, F, out, NE);
}

// Round 3
// 909.089 us; speedup vs baseline: 5.1498x; 1.1191x over previous
//
#include <hip/hip_runtime.h>

// SimpleMACELayer on gfx950 — round 3: occupancy + dense MFMA A-build.
//
//   F[h][o2][kk]   = sum_o tpw[p(kk)][h][o] * W_lin[o2][o*16 + kg(kk)]  (f16, kk pad 128, ws)
//   CGd[kk][i][j]  = cg[i][j][kg(kk)] masked to i in [b1,b1+ni), j in [b2,b2+nj)  (f16, ws)
//   A_e[kk][i]     = sum_j CGd[kk][i][j] * Y_e[j]          (dense MFMA 16x16x16f16 — no divergence)
//   U[e][h][kk]    = sum_i A_e[kk][i] * src[e][h][i]       (GEMM-1, per edge)
//   out[dst(e),:] += sum_{h,kk} U[e][h][kk] * F[h][:][kk]  (GEMM-2, 16x16x32)
//
// Round-2 post-mortem: MfmaUtil 6.8% == exactly the issued matrix work; 65% idle from
// 2 blocks/CU (76.8KB LDS) + divergent scalar A-phase + 7e7 LDS conflict cycles.
// Fix: EPB 16 => 37.9KB LDS => 4 blocks/CU; A-build as dense MFMA from precomputed CGd.

#define NKK 99
#define NKPAD 128
#define EPB 16
#define THREADS 256
#define SA_ESTR 516   // [e][kk32][i16] f16, e-stride (258 dw: conflict-free D writes)
#define SU_HSTR 40    // [e][h'16][kk32] f16, h-stride (20 dw: 2-way == free)
#define SU_ESTR 648   // e-stride (324 dw)

typedef _Float16 f16;
typedef f16 f16x4 __attribute__((ext_vector_type(4)));
typedef f16 f16x8 __attribute__((ext_vector_type(8)));
typedef float f32x4 __attribute__((ext_vector_type(4)));

__device__ __constant__ short PK_P[NKK] = {
  0, 1,1,1, 2,2,2,2,2, 3,3,3,3,3,3,3, 4,4,4, 5, 6,6,6,6,6, 7,7,7,
  8,8,8,8,8,8,8, 9,9,9,9,9, 10,10,10,10,10, 11,11,11, 12,12,12,12,12,12,12,
  13, 14,14,14,14,14, 15,15,15, 16,16,16,16,16,16,16, 17,17,17,17,17,17,17,
  18,18,18,18,18, 19,19,19, 20,20,20,20,20,20,20, 21, 22,22,22,22,22};
__device__ __constant__ short KK_L1[NKK] = {
  0, 0,0,0, 0,0,0,0,0, 0,0,0,0,0,0,0, 1,1,1, 1, 1,1,1,1,1, 1,1,1,
  1,1,1,1,1,1,1, 1,1,1,1,1, 2,2,2,2,2, 2,2,2, 2,2,2,2,2,2,2,
  2, 2,2,2,2,2, 2,2,2, 2,2,2,2,2,2,2, 3,3,3,3,3,3,3,
  3,3,3,3,3, 3,3,3, 3,3,3,3,3,3,3, 3, 3,3,3,3,3};
__device__ __constant__ short KK_L2[NKK] = {
  0, 1,1,1, 2,2,2,2,2, 3,3,3,3,3,3,3, 0,0,0, 1, 1,1,1,1,1, 2,2,2,
  2,2,2,2,2,2,2, 3,3,3,3,3, 0,0,0,0,0, 1,1,1, 1,1,1,1,1,1,1,
  2, 2,2,2,2,2, 3,3,3, 3,3,3,3,3,3,3, 0,0,0,0,0,0,0,
  1,1,1,1,1, 2,2,2, 2,2,2,2,2,2,2, 3, 3,3,3,3,3};
__device__ __constant__ short KK_KG[NKK] = {
  0, 1,2,3, 4,5,6,7,8, 9,10,11,12,13,14,15, 1,2,3, 0, 4,5,6,7,8, 1,2,3,
  9,10,11,12,13,14,15, 4,5,6,7,8, 4,5,6,7,8, 1,2,3, 9,10,11,12,13,14,15,
  0, 4,5,6,7,8, 1,2,3, 9,10,11,12,13,14,15, 9,10,11,12,13,14,15,
  4,5,6,7,8, 1,2,3, 9,10,11,12,13,14,15, 0, 4,5,6,7,8};

// ---------------- zero F (incl. kk 99..127 pad)
__global__ void zero_ws(uint4* __restrict__ F) {
  F[blockIdx.x * 256 + threadIdx.x] = uint4{0, 0, 0, 0};
}

// ---------------- F[h][o2][kk] = sum_o tpw[p][h][o] * wlin[o2][o*16+kg]
__global__ __launch_bounds__(256) void compute_F(const float* __restrict__ tpw,
                                                 const float* __restrict__ wlin,
                                                 f16* __restrict__ F) {
  int kk = blockIdx.x;
  int p  = PK_P[kk];
  int c3 = KK_KG[kk];

  __shared__ float wl[64][65];
  int tid = threadIdx.x;
  for (int idx = tid; idx < 64 * 64; idx += 256) {
    int o2 = idx >> 6, o = idx & 63;
    wl[o2][o] = wlin[o2 * 1024 + o * 16 + c3];
  }
  __syncthreads();

  int h = tid & 63, og = tid >> 6;
  float acc[16];
#pragma unroll
  for (int m = 0; m < 16; ++m) acc[m] = 0.f;
  const float* tw = tpw + (p * 64 + h) * 64;
  for (int o = 0; o < 64; ++o) {
    float w = tw[o];
#pragma unroll
    for (int m = 0; m < 16; ++m) acc[m] += w * wl[og * 16 + m][o];
  }
#pragma unroll
  for (int m = 0; m < 16; ++m)
    F[(size_t)(h * 64 + og * 16 + m) * NKPAD + kk] = (f16)acc[m];
}

// ---------------- CGd[kk][i][j]: masked-dense Gaunt slices (f16)
__global__ void compute_CGd(const float* __restrict__ cg, f16* __restrict__ CGd) {
  int kk = blockIdx.x;                 // 0..127
  int i = threadIdx.x >> 4, j = threadIdx.x & 15;
  f16 v = (f16)0.f;
  if (kk < NKK) {
    int l1 = KK_L1[kk], l2 = KK_L2[kk], kg = KK_KG[kk];
    int b1 = l1 * l1, b2 = l2 * l2;
    if (i >= b1 && i < b1 + 2 * l1 + 1 && j >= b2 && j < b2 + 2 * l2 + 1)
      v = (f16)cg[(i * 16 + j) * 16 + kg];
  }
  CGd[kk * 256 + i * 16 + j] = v;
}

// ---------------- out init
__global__ void init_out(float* __restrict__ out, const float* __restrict__ b, int n) {
  int i = blockIdx.x * 256 + threadIdx.x;
  if (i < n) out[i] = b[i & 63];
}

// ---------------- main edge kernel (16 edges/block, 37.9KB LDS -> 4 blocks/CU)
__global__ __launch_bounds__(THREADS, 4) void edge_kernel(
    const float* __restrict__ nf, const float* __restrict__ ev,
    const int* __restrict__ eidx, const f16* __restrict__ CGd,
    const f16* __restrict__ F, float* __restrict__ out, int NE) {

  __shared__ f16 sYh[EPB * 16];
  __shared__ int sSrcA[EPB];
  __shared__ int sDst[EPB];
  __shared__ f16 sA[EPB * SA_ESTR];   // 16.5KB ; reused as fp32 red[e][o2][wave] (16KB)
  __shared__ f16 sU[EPB * SU_ESTR];   // 20.7KB

  int tid = threadIdx.x;
  int wave = tid >> 6, lane = tid & 63;
  int lm = lane & 15, lq = lane >> 4;

  // --- phase 0: edge meta + spherical harmonics (f16)
  if (tid < EPB) {
    int eg = blockIdx.x * EPB + tid;
    int sa = 0, da = -1;
    float x = 0.f, y = 0.f, z = 0.f;
    if (eg < NE) {
      sa = eidx[eg];
      da = eidx[NE + eg];
      x = ev[3 * eg + 0]; y = ev[3 * eg + 1]; z = ev[3 * eg + 2];
    }
    sSrcA[tid] = sa;
    sDst[tid] = da;
    float x2 = x * x, y2 = y * y, z2 = z * z;
    float Y[16];
    Y[0]  = 0.28209479177387814f;
    Y[1]  = 0.4886025119029199f * y;
    Y[2]  = 0.4886025119029199f * z;
    Y[3]  = 0.4886025119029199f * x;
    Y[4]  = 1.0925484305920792f * x * y;
    Y[5]  = 1.0925484305920792f * y * z;
    Y[6]  = 0.31539156525252005f * (3.0f * z2 - 1.0f);
    Y[7]  = 1.0925484305920792f * x * z;
    Y[8]  = 0.5462742152960396f * (x2 - y2);
    Y[9]  = 0.5900435899266435f * y * (3.0f * x2 - y2);
    Y[10] = 2.890611442640554f * x * y * z;
    Y[11] = 0.4570457994644658f * y * (5.0f * z2 - 1.0f);
    Y[12] = 0.3731763325901154f * z * (5.0f * z2 - 3.0f);
    Y[13] = 0.4570457994644658f * x * (5.0f * z2 - 1.0f);
    Y[14] = 1.445305721320277f  * z * (x2 - y2);
    Y[15] = 0.5900435899266435f * x * (x2 - 3.0f * y2);
#pragma unroll
    for (int j = 0; j < 16; ++j) sYh[tid * 16 + j] = (f16)Y[j];
  }
  __syncthreads();

  // --- register-resident src fragments (coalesced float4 == MFMA B-layout)
  f16x4 Sf[4][4];
  int ebase = wave * 4;
#pragma unroll
  for (int ei = 0; ei < 4; ++ei) {
    const float4* src4 = (const float4*)nf + (size_t)sSrcA[ebase + ei] * 256;
#pragma unroll
    for (int hg = 0; hg < 4; ++hg) {
      float4 v = src4[(hg * 16 + lm) * 4 + lq];
      Sf[ei][hg] = f16x4{(f16)v.x, (f16)v.y, (f16)v.z, (f16)v.w};
    }
  }

  // B-frag for A-build: Y[e=lm][j=lq*4+r]
  f16x4 bY = *(const f16x4*)&sYh[lm * 16 + lq * 4];

  f32x4 acc[4];
#pragma unroll
  for (int ot = 0; ot < 4; ++ot) acc[ot] = f32x4{0.f, 0.f, 0.f, 0.f};

  for (int kg = 0; kg < 4; ++kg) {
    // --- A-build (dense MFMA): tile t covers kkloc=t, rows=i; D[n=e][m=i]
#pragma unroll
    for (int tl = 0; tl < 8; ++tl) {
      int t = wave * 8 + tl;
      f16x4 aCG = *(const f16x4*)&CGd[(size_t)(kg * 32 + t) * 256 + lm * 16 + lq * 4];
      f32x4 d = __builtin_amdgcn_mfma_f32_16x16x16f16(aCG, bY, f32x4{0.f, 0.f, 0.f, 0.f}, 0, 0, 0);
      f16x4 dh = {(f16)d[0], (f16)d[1], (f16)d[2], (f16)d[3]};
      *(f16x4*)&sA[lm * SA_ESTR + t * 16 + lq * 4] = dh;   // [e=lm][kk=t][i=lq*4+r]
    }
    __syncthreads();

#pragma unroll
    for (int hg = 0; hg < 4; ++hg) {
      // --- GEMM-1: U[kk32][h'16] per edge; A=sA rows kkloc, B=Sf
#pragma unroll
      for (int ei = 0; ei < 4; ++ei) {
        int e = ebase + ei;
        f16x4 bS = Sf[ei][hg];
#pragma unroll
        for (int mt = 0; mt < 2; ++mt) {
          f16x4 aA = *(const f16x4*)&sA[e * SA_ESTR + (mt * 16 + lm) * 16 + lq * 4];
          f32x4 d = __builtin_amdgcn_mfma_f32_16x16x16f16(aA, bS, f32x4{0.f, 0.f, 0.f, 0.f}, 0, 0, 0);
          f16x4 dh = {(f16)d[0], (f16)d[1], (f16)d[2], (f16)d[3]};
          *(f16x4*)&sU[e * SU_ESTR + lm * SU_HSTR + mt * 16 + lq * 4] = dh;  // [e][h'=lm][kk]
        }
      }
      __syncthreads();

      // --- GEMM-2: acc[e16][o2 64] += U[e][h',kk32] * F[h][o2][kk32]
#pragma unroll
      for (int hi = 0; hi < 4; ++hi) {
        int hl = wave + 4 * hi;
        int h = hg * 16 + hl;
        f16x8 a0 = *(const f16x8*)&sU[lm * SU_ESTR + hl * SU_HSTR + lq * 8];
        const f16* Fb = F + (size_t)h * 64 * NKPAD + kg * 32 + lq * 8;
#pragma unroll
        for (int ot = 0; ot < 4; ++ot) {
          f16x8 b = *(const f16x8*)&Fb[(size_t)(ot * 16 + lm) * NKPAD];
          acc[ot] = __builtin_amdgcn_mfma_f32_16x16x32_f16(a0, b, acc[ot], 0, 0, 0);
        }
      }
      __syncthreads();
    }
  }

  // --- cross-wave reduction: red[e][o2][wave] (float4-friendly) + atomic scatter
  float* red = (float*)sA;
#pragma unroll
  for (int ot = 0; ot < 4; ++ot) {
#pragma unroll
    for (int r = 0; r < 4; ++r) {
      int e = lq * 4 + r;            // D row
      int o2 = ot * 16 + lm;         // D col
      red[(e * 64 + o2) * 4 + wave] = acc[ot][r];
    }
  }
  __syncthreads();

#pragma unroll
  for (int rep = 0; rep < 4; ++rep) {
    int idx = tid + rep * 256;       // 0..1023 = e*64+o2
    float4 v = *(const float4*)&red[idx * 4];
    float s = v.x + v.y + v.z + v.w;
    int e = idx >> 6, o2 = idx & 63;
    int da = sDst[e];
    if (da >= 0) unsafeAtomicAdd(out + (size_t)da * 64 + o2, s);
  }
}

extern "C" void kernel_launch(void* const* d_in, const int* in_sizes, int n_in,
                              void* d_out, int out_size, void* d_ws, size_t ws_size,
                              hipStream_t stream) {
  const float* nf   = (const float*)d_in[0];  // [NA,64,16]
  const float* ev   = (const float*)d_in[1];  // [NE,3]
  const int*   eidx = (const int*)d_in[2];    // [2,NE]
  const float* cg   = (const float*)d_in[3];  // [16,16,16]
  const float* tpw  = (const float*)d_in[4];  // [23,64,64]
  const float* wlin = (const float*)d_in[5];  // [64,1024]
  const float* blin = (const float*)d_in[6];  // [64]
  float* out = (float*)d_out;                 // [NA,64]

  int NA = in_sizes[0] / 1024;
  int NE = in_sizes[1] / 3;
  f16* F   = (f16*)d_ws;                          // 64*64*128*2 = 1 MB
  f16* CGd = (f16*)((char*)d_ws + (size_t)64 * 64 * NKPAD * 2);  // 128*256*2 = 64 KB

  zero_ws<<<256, 256, 0, stream>>>((uint4*)F);
  compute_F<<<NKK, 256, 0, stream>>>(tpw, wlin, F);
  compute_CGd<<<NKPAD, 256, 0, stream>>>(cg, CGd);
  init_out<<<(NA * 64 + 255) / 256, 256, 0, stream>>>(out, blin, NA * 64);
  edge_kernel<<<(NE + EPB - 1) / EPB, THREADS, 0, stream>>>(nf, ev, eidx, CGd, F, out, NE);
}